// Round 2
// baseline (771.955 us; speedup 1.0000x reference)
//
#include <hip/hip_runtime.h>
#include <hip/hip_bf16.h>

#define M_NODES 32768

using f16x8 = __attribute__((ext_vector_type(8))) _Float16;
using f32x4 = __attribute__((ext_vector_type(4))) float;
typedef unsigned short u16;
typedef unsigned int   u32;

__device__ __forceinline__ u16 f2h(float f){
  _Float16 h = (_Float16)f;
  return __builtin_bit_cast(u16, h);
}
__device__ __forceinline__ float h2f(u16 h){
  return (float)__builtin_bit_cast(_Float16, h);
}
// tanh(x) = 1 - 2/(e^{2x}+1); e^{2x} = 2^{x*2*log2(e)}; saturates correctly at +-inf
__device__ __forceinline__ float tanh_fast(float x){
  float t = __builtin_amdgcn_exp2f(x * 2.8853900817779268f);
  return 1.0f - 2.0f * __builtin_amdgcn_rcpf(t + 1.0f);
}

// ---------------- prep: fp32 weights -> fp16 transposed Wt[n][k] in d_ws ----------------
// segment element offsets identical to round-1 (see stage table in front_kernel)
struct PrepPtrs { const float* p[16]; };

__global__ void prep_kernel(PrepPtrs pp, u16* ws){
  const int Bc[16] = {1,6,6,6,3,3,3,3,3,3,3,3,3,3,3,3};
  const int Kc[16] = {32,128,128,128,256,256,256,128,128,128,256,256,256,128,128,128};
  const int Nc[16] = {128,128,128,128,256,256,128,128,128,128,256,256,128,128,128,128};
  const int tot = 1576960;
  for (int i = blockIdx.x*blockDim.x + threadIdx.x; i < tot; i += gridDim.x*blockDim.x){
    int e = i, s = 0;
    while (true){ int sz = Bc[s]*Kc[s]*Nc[s]; if (e < sz) break; e -= sz; ++s; }
    int K = Kc[s], N = Nc[s];
    int kn = K*N;
    int b = e / kn; int r2 = e - b*kn;
    int n = r2 / K; int k = r2 - n*K;
    float v = pp.p[s][(size_t)b*kn + (size_t)k*N + n];
    ws[i] = f2h(v);
  }
}

// ---------------- front 0: e0 = tanh(feats0 @ embed_w + b) (fp32 vector ALU, exact) ----------------
__global__ __launch_bounds__(256) void front0_kernel(const float* __restrict__ feats,
                                                     const float* __restrict__ ew,
                                                     const float* __restrict__ eb,
                                                     float* __restrict__ out){
  __shared__ float fl[2048]; // 64 rows x 32 feats
  const int brow = blockIdx.x * 64;
  const float* f0 = feats + (size_t)brow*32;
#pragma unroll
  for (int it = 0; it < 2; ++it){
    int idx = threadIdx.x + it*256;
    *(float4*)(&fl[idx*4]) = *(const float4*)(f0 + idx*4);
  }
  __syncthreads();
  const int col = threadIdx.x & 127, rh = threadIdx.x >> 7;
  float w[32];
#pragma unroll
  for (int k = 0; k < 32; ++k) w[k] = ew[k*128 + col];
  const float bv = eb[col];
  for (int r = 0; r < 32; ++r){
    int row = rh*32 + r;
    float acc = bv;
#pragma unroll
    for (int k = 0; k < 32; ++k) acc += fl[row*32 + k] * w[k];
    out[(size_t)(brow + row)*128 + col] = tanh_fast(acc);
  }
}

// ---------------- generic MFMA stage (fp16 MFMA, fp32 accumulate) ----------------
// LDS act buffers: u16 row stride 264 (f16 view) == float row stride 132 (f32 view).
// Wave split: wid = (mh<<2)|nq ; wave owns rows [mh*64,+64), tiles {2nq,2nq+1}(+8 for NT=4)
// A-frag: row = lane&15 (+m*16), k = (lane>>4)*8+j ; B-frag from Wt[n][k] rows
// D-frag: col = lane&15, row = (lane>>4)*4 + reg
// AMODE: 0 = A fp16 in LDS, 1 = A fp32 in LDS -> 2-term hi/lo split (2x MFMA)
// RESMODE: 0 none, 1 = fp16 res only for col<128 ([x,0] concat), 2 = fp16 res, 3 = fp32 res
// OUTMODE: 0 = fp16 LDS store, 1 = fp32 LDS store, 2 = fp32 global store (final)
template<int KLOOP, int N, int WS, int AMODE, int RESMODE, int OUTMODE>
__device__ __forceinline__ void mm_stage(const u16* inA, u16* outB, const u16* resB,
                                         const u16* __restrict__ wt,
                                         const float* __restrict__ bias,
                                         float* gout, u16* WP)
{
  const int tid  = threadIdx.x;
  const int lane = tid & 63, wid = tid >> 6;
  const int mh = wid >> 2, nq = wid & 3;
  const int q = lane >> 4, c = lane & 15;
  constexpr int NT = N / 64;      // n-tiles per wave (2 or 4)
  constexpr int NP = KLOOP / 32;  // k-panels
  const float* inAf = (const float*)inA;
  float*       outF = (float*)outB;
  const float* resF = (const float*)resB;

  f32x4 acc[4][NT];
#pragma unroll
  for (int m = 0; m < 4; ++m)
#pragma unroll
    for (int j = 0; j < NT; ++j) acc[m][j] = (f32x4){0.f,0.f,0.f,0.f};

  for (int kp = 0; kp < NP; ++kp){
    // cooperative stage of weight k-panel [N][32] into padded WP[n][40]
#pragma unroll
    for (int it = 0; it < N/128; ++it){
      int tt = tid + it*512;
      int n = tt >> 2, ko = (tt & 3) * 8;
      uint4 v = *(const uint4*)(wt + (size_t)n*WS + kp*32 + ko);
      *(uint4*)(&WP[n*40 + ko]) = v;
    }
    __syncthreads();
    f16x8 bf[NT];
#pragma unroll
    for (int j = 0; j < NT; ++j){
      int nt = nq*2 + (j & 1) + (j >> 1) * 8;
      bf[j] = *(const f16x8*)(&WP[(nt*16 + c)*40 + q*8]);
    }
#pragma unroll
    for (int m = 0; m < 4; ++m){
      if (AMODE == 0){
        f16x8 af = *(const f16x8*)(&inA[(mh*64 + m*16 + c)*264 + kp*32 + q*8]);
#pragma unroll
        for (int j = 0; j < NT; ++j)
          acc[m][j] = __builtin_amdgcn_mfma_f32_16x16x32_f16(af, bf[j], acc[m][j], 0, 0, 0);
      } else {
        const float* ap = inAf + (mh*64 + m*16 + c)*132 + kp*32 + q*8;
        float4 x0 = *(const float4*)(ap);
        float4 x1 = *(const float4*)(ap + 4);
        float xs[8] = {x0.x,x0.y,x0.z,x0.w,x1.x,x1.y,x1.z,x1.w};
        f16x8 ah, al;
#pragma unroll
        for (int k = 0; k < 8; ++k){
          _Float16 hi = (_Float16)xs[k];
          ah[k] = hi;
          al[k] = (_Float16)(xs[k] - (float)hi);
        }
#pragma unroll
        for (int j = 0; j < NT; ++j){
          acc[m][j] = __builtin_amdgcn_mfma_f32_16x16x32_f16(ah, bf[j], acc[m][j], 0, 0, 0);
          acc[m][j] = __builtin_amdgcn_mfma_f32_16x16x32_f16(al, bf[j], acc[m][j], 0, 0, 0);
        }
      }
    }
    __syncthreads(); // panel reads done -> next panel may overwrite; epilogue may write in-place
  }
  // epilogue
#pragma unroll
  for (int j = 0; j < NT; ++j){
    int nt = nq*2 + (j & 1) + (j >> 1) * 8;
    int col = nt*16 + c;
    float bv = bias[col];
#pragma unroll
    for (int m = 0; m < 4; ++m){
#pragma unroll
      for (int r = 0; r < 4; ++r){
        int row = mh*64 + m*16 + q*4 + r;
        float v = tanh_fast(acc[m][j][r] + bv);
        if (RESMODE == 2)      v += h2f(resB[row*264 + col]);
        else if (RESMODE == 1){ if (col < 128) v += h2f(resB[row*264 + col]); }
        else if (RESMODE == 3) v += resF[row*132 + col];
        if (OUTMODE == 2)      gout[(size_t)row*128 + col] = v;
        else if (OUTMODE == 1) outF[row*132 + col] = v;
        else                   outB[row*264 + col] = f2h(v);
      }
    }
  }
}

// embed stage: A read directly from global fp32 feats (K=32), hi/lo split, N=128
__device__ __forceinline__ void embed_stage(const float* __restrict__ featsRow,
                                            u16* outB, const u16* __restrict__ wt,
                                            const float* __restrict__ bias, u16* WP)
{
  const int tid  = threadIdx.x;
  const int lane = tid & 63, wid = tid >> 6;
  const int mh = wid >> 2, nq = wid & 3;
  const int q = lane >> 4, c = lane & 15;
  {
    int n = tid >> 2, ko = (tid & 3) * 8;
    *(uint4*)(&WP[n*40 + ko]) = *(const uint4*)(wt + n*32 + ko);
  }
  __syncthreads();
  f16x8 bf[2];
#pragma unroll
  for (int j = 0; j < 2; ++j){
    int nt = nq*2 + j;
    bf[j] = *(const f16x8*)(&WP[(nt*16 + c)*40 + q*8]);
  }
  f32x4 acc[4][2];
#pragma unroll
  for (int m = 0; m < 4; ++m){ acc[m][0] = (f32x4){0,0,0,0}; acc[m][1] = (f32x4){0,0,0,0}; }
#pragma unroll
  for (int m = 0; m < 4; ++m){
    int row = mh*64 + m*16 + c;
    const float* fp = featsRow + (size_t)row*32 + q*8;
    float4 a0 = *(const float4*)(fp);
    float4 a1 = *(const float4*)(fp + 4);
    float xs[8] = {a0.x,a0.y,a0.z,a0.w,a1.x,a1.y,a1.z,a1.w};
    f16x8 ah, al;
#pragma unroll
    for (int k = 0; k < 8; ++k){
      _Float16 hi = (_Float16)xs[k];
      ah[k] = hi;
      al[k] = (_Float16)(xs[k] - (float)hi);
    }
#pragma unroll
    for (int j = 0; j < 2; ++j){
      acc[m][j] = __builtin_amdgcn_mfma_f32_16x16x32_f16(ah, bf[j], acc[m][j], 0, 0, 0);
      acc[m][j] = __builtin_amdgcn_mfma_f32_16x16x32_f16(al, bf[j], acc[m][j], 0, 0, 0);
    }
  }
  __syncthreads();
#pragma unroll
  for (int j = 0; j < 2; ++j){
    int nt = nq*2 + j;
    int col = nt*16 + c;
    float bv = bias[col];
#pragma unroll
    for (int m = 0; m < 4; ++m){
#pragma unroll
      for (int r = 0; r < 4; ++r){
        int row = mh*64 + m*16 + q*4 + r;
        outB[row*264 + col] = f2h(tanh_fast(acc[m][j][r] + bv));
      }
    }
  }
}

struct FrontArgs {
  const float* feats; const int* pred;
  const u16* ws;
  float* out;
  const float* embed_b;
  const float* mp_b1; const float* mp_b2; const float* mp_b3;
  const float* cw_b1; const float* cw_b2; const float* cw_b3;
  const float* ch_b1; const float* ch_b2; const float* ch_b3;
  const float* nw_b1; const float* nw_b2; const float* nw_b3;
  const float* nh_b1; const float* nh_b2; const float* nh_b3;
  int l, d;
};

// LDS: P[128][264] u16, Q[128][264] u16, WP[256][40] u16 -> 155648 B dynamic
__global__ __launch_bounds__(512, 1) void front_kernel(FrontArgs A)
{
  extern __shared__ u16 lds[];
  u16* P  = lds;
  u16* Q  = lds + 33792;
  u16* WP = lds + 67584;
  const int brow = blockIdx.x * 128;
  const int d = A.d;
  const u16* ws = A.ws;

  // ---- gather: s = sum_k prev[idx[m][k]] -> P as fp32 [128][132] ----
  {
    float* Pf = (float*)P;
    const float* prev = A.out + (size_t)(A.l - 1) * M_NODES * 128;
    const int c4 = threadIdx.x & 31;  // float4 column group
    const int r0 = threadIdx.x >> 5;  // 16 rows in flight
#pragma unroll
    for (int rr = 0; rr < 8; ++rr){
      int row = r0 + rr*16;
      const int* ip = A.pred + ((size_t)(A.l - 1) * M_NODES + brow + row) * 8;
      float sx=0.f, sy=0.f, sz=0.f, sw=0.f;
#pragma unroll
      for (int p = 0; p < 8; ++p){
        const float4 v = *(const float4*)(prev + (size_t)ip[p]*128 + c4*4);
        sx += v.x; sy += v.y; sz += v.z; sw += v.w;
      }
      float4 o = {sx, sy, sz, sw};
      *(float4*)(&Pf[row*132 + c4*4]) = o;
    }
  }
  __syncthreads();

  const int d0 = d*2, d1 = d*2 + 1;
  // ---- mp resnet pair. s and h2+s carried fp32; r1 etc fp16 ----
  // 1. h1 = tanh(s @ w1)               A=P.f32 -> Q.f16[0:128)
  mm_stage<128,128,128, 1,0,0>(P, Q, nullptr, ws + 4096   + (size_t)d0*16384, A.mp_b1 + d0*128, nullptr, WP);
  // 2. h2s = tanh(h1 @ w2) + s         A=Q.f16, res=P.f32 -> P.f32
  mm_stage<128,128,128, 0,3,1>(Q, P, P,       ws + 102400 + (size_t)d0*16384, A.mp_b2 + d0*128, nullptr, WP);
  // 3. r1 = tanh(h2s @ w3)             A=P.f32 -> Q.f16[0:128)
  mm_stage<128,128,128, 1,0,0>(P, Q, nullptr, ws + 200704 + (size_t)d0*16384, A.mp_b3 + d0*128, nullptr, WP);
  // 4. h1b = tanh(r1 @ w1)             A=Q.f16 -> P.f16[0:128)
  mm_stage<128,128,128, 0,0,0>(Q, P, nullptr, ws + 4096   + (size_t)d1*16384, A.mp_b1 + d1*128, nullptr, WP);
  // 5. h2r = tanh(h1b @ w2) + r1       A=P.f16, res=Q.f16 -> P.f32
  mm_stage<128,128,128, 0,2,1>(P, P, Q,       ws + 102400 + (size_t)d1*16384, A.mp_b2 + d1*128, nullptr, WP);
  // 6. r = tanh(h2r @ w3)              A=P.f32 -> Q.f16[128:256)
  mm_stage<128,128,128, 1,0,0>(P, Q + 128, nullptr, ws + 200704 + (size_t)d1*16384, A.mp_b3 + d1*128, nullptr, WP);

  // 7. e = tanh(feats @ ew + eb)       -> Q.f16[0:128)   (Q = [e | r])
  embed_stage(A.feats + ((size_t)A.l * M_NODES + brow) * 32, Q, ws, A.embed_b, WP);

  // ---- comb_wide resnet on [e,0] (zero-trick: K=128) ----
  // 8. h1w = tanh([e,0] @ w1)          A=Q.f16 (K=128) -> P.f16 wide
  mm_stage<128,256,256, 0,0,0>(Q, P, nullptr, ws + 299008 + (size_t)d*65536, A.cw_b1 + d*256, nullptr, WP);
  // 9. h2w = tanh(h1w @ w2) + [e,0]    in-place P, res=Q col<128
  mm_stage<256,256,256, 0,1,0>(P, P, Q,       ws + 495616 + (size_t)d*65536, A.cw_b2 + d*256, nullptr, WP);
  // 10. e2 = tanh(h2w' @ w3)           A=P wide -> Q.f16[0:128)
  mm_stage<256,128,256, 0,0,0>(P, Q, nullptr, ws + 692224 + (size_t)d*32768, A.cw_b3 + d*128, nullptr, WP);
  // ---- comb_h resnet ----
  mm_stage<128,128,128, 0,0,0>(Q, P, nullptr, ws + 790528 + (size_t)d*16384, A.ch_b1 + d*128, nullptr, WP);
  mm_stage<128,128,128, 0,2,0>(P, P, Q,       ws + 839680 + (size_t)d*16384, A.ch_b2 + d*128, nullptr, WP);
  // 13. e'' -> Q[0:128)  (Q = [e''|r] = x2)
  mm_stage<128,128,128, 0,0,0>(P, Q, nullptr, ws + 888832 + (size_t)d*16384, A.ch_b3 + d*128, nullptr, WP);
  // ---- node_wide resnet on x2 ----
  mm_stage<256,256,256, 0,0,0>(Q, P, nullptr, ws + 937984  + (size_t)d*65536, A.nw_b1 + d*256, nullptr, WP);
  mm_stage<256,256,256, 0,2,0>(P, P, Q,       ws + 1134592 + (size_t)d*65536, A.nw_b2 + d*256, nullptr, WP);
  // 16. e3 -> Q[0:128)
  mm_stage<256,128,256, 0,0,0>(P, Q, nullptr, ws + 1331200 + (size_t)d*32768, A.nw_b3 + d*128, nullptr, WP);
  // ---- node_h resnet; final stage writes fp32 to global ----
  mm_stage<128,128,128, 0,0,0>(Q, P, nullptr, ws + 1429504 + (size_t)d*16384, A.nh_b1 + d*128, nullptr, WP);
  mm_stage<128,128,128, 0,2,0>(P, P, Q,       ws + 1478656 + (size_t)d*16384, A.nh_b2 + d*128, nullptr, WP);
  float* gout = A.out + ((size_t)A.l * M_NODES + brow) * 128;
  mm_stage<128,128,128, 0,0,2>(P, nullptr, nullptr, ws + 1527808 + (size_t)d*16384, A.nh_b3 + d*128, gout, WP);
}

extern "C" void kernel_launch(void* const* d_in, const int* in_sizes, int n_in,
                              void* d_out, int out_size, void* d_ws, size_t ws_size,
                              hipStream_t stream)
{
  (void)in_sizes; (void)n_in; (void)out_size; (void)ws_size;
  const float* feats = (const float*)d_in[0];
  const int*   pred  = (const int*)d_in[1];
  u16*   ws  = (u16*)d_ws;
  float* out = (float*)d_out;

  PrepPtrs pp;
  const int wIdx[16] = {2,4,6,8,10,12,14,16,18,20,22,24,26,28,30,32};
  for (int i = 0; i < 16; ++i) pp.p[i] = (const float*)d_in[wIdx[i]];
  prep_kernel<<<2048, 256, 0, stream>>>(pp, ws);

  front0_kernel<<<M_NODES/64, 256, 0, stream>>>(feats, (const float*)d_in[2], (const float*)d_in[3], out);

  const size_t LDSB = (size_t)(2*128*264 + 256*40) * sizeof(u16); // 155648 B
  (void)hipFuncSetAttribute((const void*)front_kernel,
                            hipFuncAttributeMaxDynamicSharedMemorySize, (int)LDSB);

  FrontArgs A;
  A.feats = feats; A.pred = pred; A.ws = ws; A.out = out;
  A.embed_b = (const float*)d_in[3];
  A.mp_b1 = (const float*)d_in[5];  A.mp_b2 = (const float*)d_in[7];  A.mp_b3 = (const float*)d_in[9];
  A.cw_b1 = (const float*)d_in[11]; A.cw_b2 = (const float*)d_in[13]; A.cw_b3 = (const float*)d_in[15];
  A.ch_b1 = (const float*)d_in[17]; A.ch_b2 = (const float*)d_in[19]; A.ch_b3 = (const float*)d_in[21];
  A.nw_b1 = (const float*)d_in[23]; A.nw_b2 = (const float*)d_in[25]; A.nw_b3 = (const float*)d_in[27];
  A.nh_b1 = (const float*)d_in[29]; A.nh_b2 = (const float*)d_in[31]; A.nh_b3 = (const float*)d_in[33];

  for (int l = 1; l < 8; ++l){
    A.l = l;
    A.d = (l - 1 < 2) ? (l - 1) : 2;
    front_kernel<<<M_NODES/128, 512, LDSB, stream>>>(A);
  }
}

// Round 4
// 700.623 us; speedup vs baseline: 1.1018x; 1.1018x over previous
//
#include <hip/hip_runtime.h>
#include <hip/hip_bf16.h>

#define M_NODES 32768

using f16x8 = __attribute__((ext_vector_type(8))) _Float16;
using f32x4 = __attribute__((ext_vector_type(4))) float;
typedef unsigned short u16;
typedef unsigned int   u32;

__device__ __forceinline__ u16 f2h(float f){
  _Float16 h = (_Float16)f;
  return __builtin_bit_cast(u16, h);
}
__device__ __forceinline__ float h2f(u16 h){
  return (float)__builtin_bit_cast(_Float16, h);
}
// tanh(x) = 1 - 2/(e^{2x}+1); saturates correctly at +-inf
__device__ __forceinline__ float tanh_fast(float x){
  float t = __builtin_amdgcn_exp2f(x * 2.8853900817779268f);
  return 1.0f - 2.0f * __builtin_amdgcn_rcpf(t + 1.0f);
}

// ---------------- prep: fp32 weights -> fp16 transposed Wt[n][k] in d_ws ----------------
struct PrepPtrs { const float* p[16]; };

__global__ void prep_kernel(PrepPtrs pp, u16* ws){
  const int Bc[16] = {1,6,6,6,3,3,3,3,3,3,3,3,3,3,3,3};
  const int Kc[16] = {32,128,128,128,256,256,256,128,128,128,256,256,256,128,128,128};
  const int Nc[16] = {128,128,128,128,256,256,128,128,128,128,256,256,128,128,128,128};
  const int tot = 1576960;
  for (int i = blockIdx.x*blockDim.x + threadIdx.x; i < tot; i += gridDim.x*blockDim.x){
    int e = i, s = 0;
    while (true){ int sz = Bc[s]*Kc[s]*Nc[s]; if (e < sz) break; e -= sz; ++s; }
    int K = Kc[s], N = Nc[s];
    int kn = K*N;
    int b = e / kn; int r2 = e - b*kn;
    int n = r2 / K; int k = r2 - n*K;
    float v = pp.p[s][(size_t)b*kn + (size_t)k*N + n];
    ws[i] = f2h(v);
  }
}

// ---------------- front 0: e0 = tanh(feats0 @ embed_w + b) (fp32 vector ALU, exact) ----------------
__global__ __launch_bounds__(256) void front0_kernel(const float* __restrict__ feats,
                                                     const float* __restrict__ ew,
                                                     const float* __restrict__ eb,
                                                     float* __restrict__ out){
  __shared__ float fl[2048]; // 64 rows x 32 feats
  const int brow = blockIdx.x * 64;
  const float* f0 = feats + (size_t)brow*32;
#pragma unroll
  for (int it = 0; it < 2; ++it){
    int idx = threadIdx.x + it*256;
    *(float4*)(&fl[idx*4]) = *(const float4*)(f0 + idx*4);
  }
  __syncthreads();
  const int col = threadIdx.x & 127, rh = threadIdx.x >> 7;
  float w[32];
#pragma unroll
  for (int k = 0; k < 32; ++k) w[k] = ew[k*128 + col];
  const float bv = eb[col];
  for (int r = 0; r < 32; ++r){
    int row = rh*32 + r;
    float acc = bv;
#pragma unroll
    for (int k = 0; k < 32; ++k) acc += fl[row*32 + k] * w[k];
    out[(size_t)(brow + row)*128 + col] = tanh_fast(acc);
  }
}

// ---------------- generic MFMA stage (fp16 MFMA, fp32 accumulate) ----------------
// 64-row block, 4 waves (wid = nq owns col tiles). B-fragments loaded DIRECTLY from
// global (L2-resident d_ws) into registers, prefetch depth 2 — no LDS staging, no
// per-panel barriers. One __syncthreads at stage end; extra pre-epilogue barrier
// when output overlaps a same-stage input read by other waves (INPLACE).
// LDS act buffers: u16 row stride 264 (f16 view) == float row stride 132 (f32 view).
// A-frag: row = m*16 + (lane&15), k = (lane>>4)*8+j ; B-frag from Wt[n][k] rows.
// D-frag: col = lane&15, row = (lane>>4)*4 + reg.
// AMODE: 0 = A fp16 in LDS, 1 = A fp32 in LDS -> hi/lo split (2x MFMA)
// RESMODE: 0 none, 1 fp16 res col<128 only, 2 fp16 res, 3 fp32 res
// OUTMODE: 0 fp16 LDS, 1 fp32 LDS, 2 fp32 global (final)
template<int KLOOP, int N, int WS, int AMODE, int RESMODE, int OUTMODE, bool INPLACE>
__device__ __forceinline__ void mm_stage(const u16* inA, u16* outB, const u16* resB,
                                         const u16* __restrict__ wt,
                                         const float* __restrict__ bias,
                                         float* gout)
{
  const int tid  = threadIdx.x;
  const int lane = tid & 63, nq = tid >> 6;
  const int q = lane >> 4, c = lane & 15;
  constexpr int NT = N / 64;      // col tiles per wave (2 or 4)
  constexpr int NP = KLOOP / 32;  // k-panels (4 or 8)
  const float* inAf = (const float*)inA;
  float*       outF = (float*)outB;
  const float* resF = (const float*)resB;

  const u16* wrow[NT];
#pragma unroll
  for (int j = 0; j < NT; ++j){
    int nt = nq*2 + (j & 1) + (j >> 1) * 8;
    wrow[j] = wt + (size_t)(nt*16 + c)*WS + q*8;
  }
  f16x8 breg[2][NT];
#pragma unroll
  for (int j = 0; j < NT; ++j) breg[0][j] = *(const f16x8*)(wrow[j]);
#pragma unroll
  for (int j = 0; j < NT; ++j) breg[1][j] = *(const f16x8*)(wrow[j] + 32);

  f32x4 acc[4][NT];
#pragma unroll
  for (int m = 0; m < 4; ++m)
#pragma unroll
    for (int j = 0; j < NT; ++j) acc[m][j] = (f32x4){0.f,0.f,0.f,0.f};

#pragma unroll
  for (int kp = 0; kp < NP; ++kp){
    f16x8 bc[NT];
#pragma unroll
    for (int j = 0; j < NT; ++j) bc[j] = breg[kp & 1][j];
    if (kp + 2 < NP){
#pragma unroll
      for (int j = 0; j < NT; ++j) breg[kp & 1][j] = *(const f16x8*)(wrow[j] + (kp + 2)*32);
    }
#pragma unroll
    for (int m = 0; m < 4; ++m){
      if (AMODE == 0){
        f16x8 af = *(const f16x8*)(&inA[(m*16 + c)*264 + kp*32 + q*8]);
#pragma unroll
        for (int j = 0; j < NT; ++j)
          acc[m][j] = __builtin_amdgcn_mfma_f32_16x16x32_f16(af, bc[j], acc[m][j], 0, 0, 0);
      } else {
        const float* ap = inAf + (m*16 + c)*132 + kp*32 + q*8;
        float4 x0 = *(const float4*)(ap);
        float4 x1 = *(const float4*)(ap + 4);
        float xs[8] = {x0.x,x0.y,x0.z,x0.w,x1.x,x1.y,x1.z,x1.w};
        f16x8 ah, al;
#pragma unroll
        for (int k = 0; k < 8; ++k){
          _Float16 hi = (_Float16)xs[k];
          ah[k] = hi;
          al[k] = (_Float16)(xs[k] - (float)hi);
        }
#pragma unroll
        for (int j = 0; j < NT; ++j){
          acc[m][j] = __builtin_amdgcn_mfma_f32_16x16x32_f16(ah, bc[j], acc[m][j], 0, 0, 0);
          acc[m][j] = __builtin_amdgcn_mfma_f32_16x16x32_f16(al, bc[j], acc[m][j], 0, 0, 0);
        }
      }
    }
  }
  if (INPLACE) __syncthreads();
  // epilogue
#pragma unroll
  for (int j = 0; j < NT; ++j){
    int nt = nq*2 + (j & 1) + (j >> 1) * 8;
    int col = nt*16 + c;
    float bv = bias[col];
#pragma unroll
    for (int m = 0; m < 4; ++m){
#pragma unroll
      for (int r = 0; r < 4; ++r){
        int row = m*16 + q*4 + r;
        float v = tanh_fast(acc[m][j][r] + bv);
        if (RESMODE == 2)      v += h2f(resB[row*264 + col]);
        else if (RESMODE == 1){ if (col < 128) v += h2f(resB[row*264 + col]); }
        else if (RESMODE == 3) v += resF[row*132 + col];
        if (OUTMODE == 2)      gout[(size_t)row*128 + col] = v;
        else if (OUTMODE == 1) outF[row*132 + col] = v;
        else                   outB[row*264 + col] = f2h(v);
      }
    }
  }
  __syncthreads();
}

// embed stage: A from global fp32 feats (K=32) hi/lo split; B direct from global
__device__ __forceinline__ void embed_stage(const float* __restrict__ featsRow,
                                            u16* outB, const u16* __restrict__ wt,
                                            const float* __restrict__ bias)
{
  const int tid  = threadIdx.x;
  const int lane = tid & 63, nq = tid >> 6;
  const int q = lane >> 4, c = lane & 15;
  f16x8 bf[2];
#pragma unroll
  for (int j = 0; j < 2; ++j){
    int nt = nq*2 + j;
    bf[j] = *(const f16x8*)(wt + (nt*16 + c)*32 + q*8);
  }
  f32x4 acc[4][2];
#pragma unroll
  for (int m = 0; m < 4; ++m){ acc[m][0] = (f32x4){0,0,0,0}; acc[m][1] = (f32x4){0,0,0,0}; }
#pragma unroll
  for (int m = 0; m < 4; ++m){
    int row = m*16 + c;
    const float* fp = featsRow + (size_t)row*32 + q*8;
    float4 a0 = *(const float4*)(fp);
    float4 a1 = *(const float4*)(fp + 4);
    float xs[8] = {a0.x,a0.y,a0.z,a0.w,a1.x,a1.y,a1.z,a1.w};
    f16x8 ah, al;
#pragma unroll
    for (int k = 0; k < 8; ++k){
      _Float16 hi = (_Float16)xs[k];
      ah[k] = hi;
      al[k] = (_Float16)(xs[k] - (float)hi);
    }
#pragma unroll
    for (int j = 0; j < 2; ++j){
      acc[m][j] = __builtin_amdgcn_mfma_f32_16x16x32_f16(ah, bf[j], acc[m][j], 0, 0, 0);
      acc[m][j] = __builtin_amdgcn_mfma_f32_16x16x32_f16(al, bf[j], acc[m][j], 0, 0, 0);
    }
  }
#pragma unroll
  for (int j = 0; j < 2; ++j){
    int nt = nq*2 + j;
    int col = nt*16 + c;
    float bv = bias[col];
#pragma unroll
    for (int m = 0; m < 4; ++m){
#pragma unroll
      for (int r = 0; r < 4; ++r){
        int row = m*16 + q*4 + r;
        outB[row*264 + col] = f2h(tanh_fast(acc[m][j][r] + bv));
      }
    }
  }
  __syncthreads();
}

struct FrontArgs {
  const float* feats; const int* pred;
  const u16* ws;
  float* out;
  const float* embed_b;
  const float* mp_b1; const float* mp_b2; const float* mp_b3;
  const float* cw_b1; const float* cw_b2; const float* cw_b3;
  const float* ch_b1; const float* ch_b2; const float* ch_b3;
  const float* nw_b1; const float* nw_b2; const float* nw_b3;
  const float* nh_b1; const float* nh_b2; const float* nh_b3;
  int l, d;
};

// LDS: P[64][264] u16 + Q[64][264] u16 = 67584 B dynamic -> 2 blocks/CU
__global__ __launch_bounds__(256, 2) void front_kernel(FrontArgs A)
{
  extern __shared__ u16 lds[];
  u16* P  = lds;
  u16* Q  = lds + 16896;
  const int brow = blockIdx.x * 64;
  const int d = A.d;
  const u16* ws = A.ws;

  // ---- gather: s = sum_k prev[idx[m][k]] -> P as fp32 [64][132] ----
  {
    float* Pf = (float*)P;
    const float* prev = A.out + (size_t)(A.l - 1) * M_NODES * 128;
    const int c4 = threadIdx.x & 31;  // float4 column group
    const int r0 = threadIdx.x >> 5;  // 8 rows in flight
#pragma unroll
    for (int rr = 0; rr < 8; ++rr){
      int row = r0 + rr*8;
      const int* ip = A.pred + ((size_t)(A.l - 1) * M_NODES + brow + row) * 8;
      float sx=0.f, sy=0.f, sz=0.f, sw=0.f;
#pragma unroll
      for (int p = 0; p < 8; ++p){
        const float4 v = *(const float4*)(prev + (size_t)ip[p]*128 + c4*4);
        sx += v.x; sy += v.y; sz += v.z; sw += v.w;
      }
      float4 o = {sx, sy, sz, sw};
      *(float4*)(&Pf[row*132 + c4*4]) = o;
    }
  }
  __syncthreads();

  const int d0 = d*2, d1 = d*2 + 1;
  // 1. h1 = tanh(s @ w1)               A=P.f32 -> Q.f16[0:128)
  mm_stage<128,128,128, 1,0,0,false>(P, Q, nullptr, ws + 4096   + (size_t)d0*16384, A.mp_b1 + d0*128, nullptr);
  // 2. h2s = tanh(h1 @ w2) + s         A=Q.f16, res=P.f32 -> P.f32 (per-thread identity, safe)
  mm_stage<128,128,128, 0,3,1,false>(Q, P, P,       ws + 102400 + (size_t)d0*16384, A.mp_b2 + d0*128, nullptr);
  // 3. r1 = tanh(h2s @ w3)             A=P.f32 -> Q.f16[0:128)
  mm_stage<128,128,128, 1,0,0,false>(P, Q, nullptr, ws + 200704 + (size_t)d0*16384, A.mp_b3 + d0*128, nullptr);
  // 4. h1b = tanh(r1 @ w1)             A=Q.f16 -> P.f16[0:128)
  mm_stage<128,128,128, 0,0,0,false>(Q, P, nullptr, ws + 4096   + (size_t)d1*16384, A.mp_b1 + d1*128, nullptr);
  // 5. h2r = tanh(h1b @ w2) + r1       A=P.f16, res=Q.f16 -> P.f32 (layout change: INPLACE)
  mm_stage<128,128,128, 0,2,1,true >(P, P, Q,       ws + 102400 + (size_t)d1*16384, A.mp_b2 + d1*128, nullptr);
  // 6. r = tanh(h2r @ w3)              A=P.f32 -> Q.f16[128:256)
  mm_stage<128,128,128, 1,0,0,false>(P, Q + 128, nullptr, ws + 200704 + (size_t)d1*16384, A.mp_b3 + d1*128, nullptr);
  // 7. e -> Q.f16[0:128)   (Q = [e | r])
  embed_stage(A.feats + ((size_t)A.l * M_NODES + brow) * 32, Q, ws, A.embed_b);
  // ---- comb_wide resnet on [e,0] (zero-trick: K=128) ----
  mm_stage<128,256,256, 0,0,0,false>(Q, P, nullptr, ws + 299008 + (size_t)d*65536, A.cw_b1 + d*256, nullptr);
  mm_stage<256,256,256, 0,1,0,true >(P, P, Q,       ws + 495616 + (size_t)d*65536, A.cw_b2 + d*256, nullptr);
  mm_stage<256,128,256, 0,0,0,false>(P, Q, nullptr, ws + 692224 + (size_t)d*32768, A.cw_b3 + d*128, nullptr);
  // ---- comb_h resnet ----
  mm_stage<128,128,128, 0,0,0,false>(Q, P, nullptr, ws + 790528 + (size_t)d*16384, A.ch_b1 + d*128, nullptr);
  mm_stage<128,128,128, 0,2,0,true >(P, P, Q,       ws + 839680 + (size_t)d*16384, A.ch_b2 + d*128, nullptr);
  mm_stage<128,128,128, 0,0,0,false>(P, Q, nullptr, ws + 888832 + (size_t)d*16384, A.ch_b3 + d*128, nullptr);
  // ---- node_wide resnet on x2 = [e''|r] in Q ----
  mm_stage<256,256,256, 0,0,0,false>(Q, P, nullptr, ws + 937984  + (size_t)d*65536, A.nw_b1 + d*256, nullptr);
  mm_stage<256,256,256, 0,2,0,true >(P, P, Q,       ws + 1134592 + (size_t)d*65536, A.nw_b2 + d*256, nullptr);
  mm_stage<256,128,256, 0,0,0,false>(P, Q, nullptr, ws + 1331200 + (size_t)d*32768, A.nw_b3 + d*128, nullptr);
  // ---- node_h resnet; final writes fp32 to global ----
  mm_stage<128,128,128, 0,0,0,false>(Q, P, nullptr, ws + 1429504 + (size_t)d*16384, A.nh_b1 + d*128, nullptr);
  mm_stage<128,128,128, 0,2,0,true >(P, P, Q,       ws + 1478656 + (size_t)d*16384, A.nh_b2 + d*128, nullptr);
  float* gout = A.out + ((size_t)A.l * M_NODES + brow) * 128;
  mm_stage<128,128,128, 0,0,2,false>(P, nullptr, nullptr, ws + 1527808 + (size_t)d*16384, A.nh_b3 + d*128, gout);
}

extern "C" void kernel_launch(void* const* d_in, const int* in_sizes, int n_in,
                              void* d_out, int out_size, void* d_ws, size_t ws_size,
                              hipStream_t stream)
{
  (void)in_sizes; (void)n_in; (void)out_size; (void)ws_size;
  const float* feats = (const float*)d_in[0];
  const int*   pred  = (const int*)d_in[1];
  u16*   ws  = (u16*)d_ws;
  float* out = (float*)d_out;

  PrepPtrs pp;
  const int wIdx[16] = {2,4,6,8,10,12,14,16,18,20,22,24,26,28,30,32};
  for (int i = 0; i < 16; ++i) pp.p[i] = (const float*)d_in[wIdx[i]];
  prep_kernel<<<2048, 256, 0, stream>>>(pp, ws);

  front0_kernel<<<M_NODES/64, 256, 0, stream>>>(feats, (const float*)d_in[2], (const float*)d_in[3], out);

  const size_t LDSB = (size_t)(2*64*264) * sizeof(u16); // 67584 B
  (void)hipFuncSetAttribute((const void*)front_kernel,
                            hipFuncAttributeMaxDynamicSharedMemorySize, (int)LDSB);

  FrontArgs A;
  A.feats = feats; A.pred = pred; A.ws = ws; A.out = out;
  A.embed_b = (const float*)d_in[3];
  A.mp_b1 = (const float*)d_in[5];  A.mp_b2 = (const float*)d_in[7];  A.mp_b3 = (const float*)d_in[9];
  A.cw_b1 = (const float*)d_in[11]; A.cw_b2 = (const float*)d_in[13]; A.cw_b3 = (const float*)d_in[15];
  A.ch_b1 = (const float*)d_in[17]; A.ch_b2 = (const float*)d_in[19]; A.ch_b3 = (const float*)d_in[21];
  A.nw_b1 = (const float*)d_in[23]; A.nw_b2 = (const float*)d_in[25]; A.nw_b3 = (const float*)d_in[27];
  A.nh_b1 = (const float*)d_in[29]; A.nh_b2 = (const float*)d_in[31]; A.nh_b3 = (const float*)d_in[33];

  for (int l = 1; l < 8; ++l){
    A.l = l;
    A.d = (l - 1 < 2) ? (l - 1) : 2;
    front_kernel<<<M_NODES/64, 256, LDSB, stream>>>(A);
  }
}

// Round 5
// 694.808 us; speedup vs baseline: 1.1110x; 1.0084x over previous
//
#include <hip/hip_runtime.h>
#include <hip/hip_bf16.h>

#define M_NODES 32768

using f16x8 = __attribute__((ext_vector_type(8))) _Float16;
using f32x4 = __attribute__((ext_vector_type(4))) float;
typedef unsigned short u16;
typedef unsigned int   u32;

__device__ __forceinline__ u16 f2h(float f){
  _Float16 h = (_Float16)f;
  return __builtin_bit_cast(u16, h);
}
__device__ __forceinline__ float h2f(u16 h){
  return (float)__builtin_bit_cast(_Float16, h);
}
// tanh(x) = 1 - 2/(e^{2x}+1); saturates correctly at +-inf
__device__ __forceinline__ float tanh_fast(float x){
  float t = __builtin_amdgcn_exp2f(x * 2.8853900817779268f);
  return 1.0f - 2.0f * __builtin_amdgcn_rcpf(t + 1.0f);
}

// ---------------- prep: fp32 weights -> fp16 transposed Wt[n][k] in d_ws ----------------
struct PrepPtrs { const float* p[16]; };

__global__ void prep_kernel(PrepPtrs pp, u16* ws){
  const int Bc[16] = {1,6,6,6,3,3,3,3,3,3,3,3,3,3,3,3};
  const int Kc[16] = {32,128,128,128,256,256,256,128,128,128,256,256,256,128,128,128};
  const int Nc[16] = {128,128,128,128,256,256,128,128,128,128,256,256,128,128,128,128};
  const int tot = 1576960;
  for (int i = blockIdx.x*blockDim.x + threadIdx.x; i < tot; i += gridDim.x*blockDim.x){
    int e = i, s = 0;
    while (true){ int sz = Bc[s]*Kc[s]*Nc[s]; if (e < sz) break; e -= sz; ++s; }
    int K = Kc[s], N = Nc[s];
    int kn = K*N;
    int b = e / kn; int r2 = e - b*kn;
    int n = r2 / K; int k = r2 - n*K;
    float v = pp.p[s][(size_t)b*kn + (size_t)k*N + n];
    ws[i] = f2h(v);
  }
}

// ---------------- front 0: e0 = tanh(feats0 @ embed_w + b) (fp32 vector ALU, exact) ----------------
__global__ __launch_bounds__(256) void front0_kernel(const float* __restrict__ feats,
                                                     const float* __restrict__ ew,
                                                     const float* __restrict__ eb,
                                                     float* __restrict__ out){
  __shared__ float fl[2048]; // 64 rows x 32 feats
  const int brow = blockIdx.x * 64;
  const float* f0 = feats + (size_t)brow*32;
#pragma unroll
  for (int it = 0; it < 2; ++it){
    int idx = threadIdx.x + it*256;
    *(float4*)(&fl[idx*4]) = *(const float4*)(f0 + idx*4);
  }
  __syncthreads();
  const int col = threadIdx.x & 127, rh = threadIdx.x >> 7;
  float w[32];
#pragma unroll
  for (int k = 0; k < 32; ++k) w[k] = ew[k*128 + col];
  const float bv = eb[col];
  for (int r = 0; r < 32; ++r){
    int row = rh*32 + r;
    float acc = bv;
#pragma unroll
    for (int k = 0; k < 32; ++k) acc += fl[row*32 + k] * w[k];
    out[(size_t)(brow + row)*128 + col] = tanh_fast(acc);
  }
}

// ---------------- generic MFMA stage (fp16 MFMA, fp32 accumulate) ----------------
// 64-row block, 4 waves. B-fragments loaded DIRECTLY from global (L2-resident d_ws)
// into a 4-deep register ring (full-stage preload when NP<=4). Per-block K-panel
// PHASE ROTATION decorrelates the L2 lines that concurrently-running blocks touch
// (all blocks share the same weights -> lock-step = same-line channel hotspot).
// Accumulation is order-independent, so rotation is numerically benign.
// LDS act buffers: u16 row stride 264 (f16 view) == float row stride 132 (f32 view).
// A-frag: row = m*16 + (lane&15), k = (lane>>4)*8+j ; B-frag from Wt[n][k] rows.
// D-frag: col = lane&15, row = (lane>>4)*4 + reg.
// AMODE: 0 = A fp16 in LDS, 1 = A fp32 in LDS -> hi/lo split (2x MFMA)
// RESMODE: 0 none, 1 fp16 res col<128 only, 2 fp16 res, 3 fp32 res
// OUTMODE: 0 fp16 LDS, 1 fp32 LDS, 2 fp32 global (final)
template<int KLOOP, int N, int WS, int AMODE, int RESMODE, int OUTMODE, bool INPLACE>
__device__ __forceinline__ void mm_stage(const u16* inA, u16* outB, const u16* resB,
                                         const u16* __restrict__ wt,
                                         const float* __restrict__ bias,
                                         float* gout, int phase)
{
  const int tid  = threadIdx.x;
  const int lane = tid & 63, nq = tid >> 6;
  const int q = lane >> 4, c = lane & 15;
  constexpr int NT = N / 64;      // col tiles per wave (2 or 4)
  constexpr int NP = KLOOP / 32;  // k-panels (4 or 8)
  constexpr int DEPTH = (NP < 4) ? NP : 4;
  const float* inAf = (const float*)inA;
  float*       outF = (float*)outB;
  const float* resF = (const float*)resB;
  const int ph = phase & (NP - 1);

  const u16* wrow[NT];
#pragma unroll
  for (int j = 0; j < NT; ++j){
    int nt = nq*2 + (j & 1) + (j >> 1) * 8;
    wrow[j] = wt + (size_t)(nt*16 + c)*WS + q*8;
  }
  // preload DEPTH panels (rotated)
  f16x8 breg[DEPTH][NT];
#pragma unroll
  for (int p = 0; p < DEPTH; ++p){
    int kpp = (ph + p) & (NP - 1);
#pragma unroll
    for (int j = 0; j < NT; ++j) breg[p][j] = *(const f16x8*)(wrow[j] + kpp*32);
  }

  f32x4 acc[4][NT];
#pragma unroll
  for (int m = 0; m < 4; ++m)
#pragma unroll
    for (int j = 0; j < NT; ++j) acc[m][j] = (f32x4){0.f,0.f,0.f,0.f};

#pragma unroll
  for (int kp = 0; kp < NP; ++kp){
    const int slot = kp & (DEPTH - 1);
    const int kpp = (ph + kp) & (NP - 1);
    f16x8 bc[NT];
#pragma unroll
    for (int j = 0; j < NT; ++j) bc[j] = breg[slot][j];
    if (kp + DEPTH < NP){
      int kpn = (ph + kp + DEPTH) & (NP - 1);
#pragma unroll
      for (int j = 0; j < NT; ++j) breg[slot][j] = *(const f16x8*)(wrow[j] + kpn*32);
    }
#pragma unroll
    for (int m = 0; m < 4; ++m){
      if (AMODE == 0){
        f16x8 af = *(const f16x8*)(&inA[(m*16 + c)*264 + kpp*32 + q*8]);
#pragma unroll
        for (int j = 0; j < NT; ++j)
          acc[m][j] = __builtin_amdgcn_mfma_f32_16x16x32_f16(af, bc[j], acc[m][j], 0, 0, 0);
      } else {
        const float* ap = inAf + (m*16 + c)*132 + kpp*32 + q*8;
        float4 x0 = *(const float4*)(ap);
        float4 x1 = *(const float4*)(ap + 4);
        float xs[8] = {x0.x,x0.y,x0.z,x0.w,x1.x,x1.y,x1.z,x1.w};
        f16x8 ah, al;
#pragma unroll
        for (int k = 0; k < 8; ++k){
          _Float16 hi = (_Float16)xs[k];
          ah[k] = hi;
          al[k] = (_Float16)(xs[k] - (float)hi);
        }
#pragma unroll
        for (int j = 0; j < NT; ++j){
          acc[m][j] = __builtin_amdgcn_mfma_f32_16x16x32_f16(ah, bc[j], acc[m][j], 0, 0, 0);
          acc[m][j] = __builtin_amdgcn_mfma_f32_16x16x32_f16(al, bc[j], acc[m][j], 0, 0, 0);
        }
      }
    }
  }
  if (INPLACE) __syncthreads();
  // epilogue
#pragma unroll
  for (int j = 0; j < NT; ++j){
    int nt = nq*2 + (j & 1) + (j >> 1) * 8;
    int col = nt*16 + c;
    float bv = bias[col];
#pragma unroll
    for (int m = 0; m < 4; ++m){
#pragma unroll
      for (int r = 0; r < 4; ++r){
        int row = m*16 + q*4 + r;
        float v = tanh_fast(acc[m][j][r] + bv);
        if (RESMODE == 2)      v += h2f(resB[row*264 + col]);
        else if (RESMODE == 1){ if (col < 128) v += h2f(resB[row*264 + col]); }
        else if (RESMODE == 3) v += resF[row*132 + col];
        if (OUTMODE == 2)      gout[(size_t)row*128 + col] = v;
        else if (OUTMODE == 1) outF[row*132 + col] = v;
        else                   outB[row*264 + col] = f2h(v);
      }
    }
  }
  __syncthreads();
}

// embed stage: A from global fp32 feats (K=32) hi/lo split; B direct from global
__device__ __forceinline__ void embed_stage(const float* __restrict__ featsRow,
                                            u16* outB, const u16* __restrict__ wt,
                                            const float* __restrict__ bias)
{
  const int tid  = threadIdx.x;
  const int lane = tid & 63, nq = tid >> 6;
  const int q = lane >> 4, c = lane & 15;
  f16x8 bf[2];
#pragma unroll
  for (int j = 0; j < 2; ++j){
    int nt = nq*2 + j;
    bf[j] = *(const f16x8*)(wt + (nt*16 + c)*32 + q*8);
  }
  f32x4 acc[4][2];
#pragma unroll
  for (int m = 0; m < 4; ++m){ acc[m][0] = (f32x4){0,0,0,0}; acc[m][1] = (f32x4){0,0,0,0}; }
#pragma unroll
  for (int m = 0; m < 4; ++m){
    int row = m*16 + c;
    const float* fp = featsRow + (size_t)row*32 + q*8;
    float4 a0 = *(const float4*)(fp);
    float4 a1 = *(const float4*)(fp + 4);
    float xs[8] = {a0.x,a0.y,a0.z,a0.w,a1.x,a1.y,a1.z,a1.w};
    f16x8 ah, al;
#pragma unroll
    for (int k = 0; k < 8; ++k){
      _Float16 hi = (_Float16)xs[k];
      ah[k] = hi;
      al[k] = (_Float16)(xs[k] - (float)hi);
    }
#pragma unroll
    for (int j = 0; j < 2; ++j){
      acc[m][j] = __builtin_amdgcn_mfma_f32_16x16x32_f16(ah, bf[j], acc[m][j], 0, 0, 0);
      acc[m][j] = __builtin_amdgcn_mfma_f32_16x16x32_f16(al, bf[j], acc[m][j], 0, 0, 0);
    }
  }
#pragma unroll
  for (int j = 0; j < 2; ++j){
    int nt = nq*2 + j;
    int col = nt*16 + c;
    float bv = bias[col];
#pragma unroll
    for (int m = 0; m < 4; ++m){
#pragma unroll
      for (int r = 0; r < 4; ++r){
        int row = m*16 + q*4 + r;
        outB[row*264 + col] = f2h(tanh_fast(acc[m][j][r] + bv));
      }
    }
  }
  __syncthreads();
}

struct FrontArgs {
  const float* feats; const int* pred;
  const u16* ws;
  float* out;
  const float* embed_b;
  const float* mp_b1; const float* mp_b2; const float* mp_b3;
  const float* cw_b1; const float* cw_b2; const float* cw_b3;
  const float* ch_b1; const float* ch_b2; const float* ch_b3;
  const float* nw_b1; const float* nw_b2; const float* nw_b3;
  const float* nh_b1; const float* nh_b2; const float* nh_b3;
  int l, d;
};

// LDS: P[64][264] u16 + Q[64][264] u16 = 67584 B dynamic -> 2 blocks/CU
__global__ __launch_bounds__(256, 2) void front_kernel(FrontArgs A)
{
  extern __shared__ u16 lds[];
  u16* P  = lds;
  u16* Q  = lds + 16896;
  const int brow = blockIdx.x * 64;
  const int d = A.d;
  const u16* ws = A.ws;
  const int ph = blockIdx.x;   // per-block K-panel phase (L2 de-hotspot)

  // ---- gather: s = sum_k prev[idx[m][k]] -> P as fp32 [64][132] ----
  {
    float* Pf = (float*)P;
    const float* prev = A.out + (size_t)(A.l - 1) * M_NODES * 128;
    const int c4 = threadIdx.x & 31;  // float4 column group
    const int r0 = threadIdx.x >> 5;  // 8 rows in flight
#pragma unroll
    for (int rr = 0; rr < 8; ++rr){
      int row = r0 + rr*8;
      const int* ip = A.pred + ((size_t)(A.l - 1) * M_NODES + brow + row) * 8;
      float sx=0.f, sy=0.f, sz=0.f, sw=0.f;
#pragma unroll
      for (int p = 0; p < 8; ++p){
        const float4 v = *(const float4*)(prev + (size_t)ip[p]*128 + c4*4);
        sx += v.x; sy += v.y; sz += v.z; sw += v.w;
      }
      float4 o = {sx, sy, sz, sw};
      *(float4*)(&Pf[row*132 + c4*4]) = o;
    }
  }
  __syncthreads();

  const int d0 = d*2, d1 = d*2 + 1;
  // 1. h1 = tanh(s @ w1)               A=P.f32 -> Q.f16[0:128)
  mm_stage<128,128,128, 1,0,0,false>(P, Q, nullptr, ws + 4096   + (size_t)d0*16384, A.mp_b1 + d0*128, nullptr, ph);
  // 2. h2s = tanh(h1 @ w2) + s         A=Q.f16, res=P.f32 -> P.f32 (per-thread identity, safe)
  mm_stage<128,128,128, 0,3,1,false>(Q, P, P,       ws + 102400 + (size_t)d0*16384, A.mp_b2 + d0*128, nullptr, ph);
  // 3. r1 = tanh(h2s @ w3)             A=P.f32 -> Q.f16[0:128)
  mm_stage<128,128,128, 1,0,0,false>(P, Q, nullptr, ws + 200704 + (size_t)d0*16384, A.mp_b3 + d0*128, nullptr, ph);
  // 4. h1b = tanh(r1 @ w1)             A=Q.f16 -> P.f16[0:128)
  mm_stage<128,128,128, 0,0,0,false>(Q, P, nullptr, ws + 4096   + (size_t)d1*16384, A.mp_b1 + d1*128, nullptr, ph);
  // 5. h2r = tanh(h1b @ w2) + r1       A=P.f16, res=Q.f16 -> P.f32 (layout change: INPLACE)
  mm_stage<128,128,128, 0,2,1,true >(P, P, Q,       ws + 102400 + (size_t)d1*16384, A.mp_b2 + d1*128, nullptr, ph);
  // 6. r = tanh(h2r @ w3)              A=P.f32 -> Q.f16[128:256)
  mm_stage<128,128,128, 1,0,0,false>(P, Q + 128, nullptr, ws + 200704 + (size_t)d1*16384, A.mp_b3 + d1*128, nullptr, ph);
  // 7. e -> Q.f16[0:128)   (Q = [e | r])
  embed_stage(A.feats + ((size_t)A.l * M_NODES + brow) * 32, Q, ws, A.embed_b);
  // ---- comb_wide resnet on [e,0] (zero-trick: K=128) ----
  mm_stage<128,256,256, 0,0,0,false>(Q, P, nullptr, ws + 299008 + (size_t)d*65536, A.cw_b1 + d*256, nullptr, ph);
  mm_stage<256,256,256, 0,1,0,true >(P, P, Q,       ws + 495616 + (size_t)d*65536, A.cw_b2 + d*256, nullptr, ph);
  mm_stage<256,128,256, 0,0,0,false>(P, Q, nullptr, ws + 692224 + (size_t)d*32768, A.cw_b3 + d*128, nullptr, ph);
  // ---- comb_h resnet ----
  mm_stage<128,128,128, 0,0,0,false>(Q, P, nullptr, ws + 790528 + (size_t)d*16384, A.ch_b1 + d*128, nullptr, ph);
  mm_stage<128,128,128, 0,2,0,true >(P, P, Q,       ws + 839680 + (size_t)d*16384, A.ch_b2 + d*128, nullptr, ph);
  mm_stage<128,128,128, 0,0,0,false>(P, Q, nullptr, ws + 888832 + (size_t)d*16384, A.ch_b3 + d*128, nullptr, ph);
  // ---- node_wide resnet on x2 = [e''|r] in Q ----
  mm_stage<256,256,256, 0,0,0,false>(Q, P, nullptr, ws + 937984  + (size_t)d*65536, A.nw_b1 + d*256, nullptr, ph);
  mm_stage<256,256,256, 0,2,0,true >(P, P, Q,       ws + 1134592 + (size_t)d*65536, A.nw_b2 + d*256, nullptr, ph);
  mm_stage<256,128,256, 0,0,0,false>(P, Q, nullptr, ws + 1331200 + (size_t)d*32768, A.nw_b3 + d*128, nullptr, ph);
  // ---- node_h resnet; final writes fp32 to global ----
  mm_stage<128,128,128, 0,0,0,false>(Q, P, nullptr, ws + 1429504 + (size_t)d*16384, A.nh_b1 + d*128, nullptr, ph);
  mm_stage<128,128,128, 0,2,0,true >(P, P, Q,       ws + 1478656 + (size_t)d*16384, A.nh_b2 + d*128, nullptr, ph);
  float* gout = A.out + ((size_t)A.l * M_NODES + brow) * 128;
  mm_stage<128,128,128, 0,0,2,false>(P, nullptr, nullptr, ws + 1527808 + (size_t)d*16384, A.nh_b3 + d*128, gout, ph);
}

extern "C" void kernel_launch(void* const* d_in, const int* in_sizes, int n_in,
                              void* d_out, int out_size, void* d_ws, size_t ws_size,
                              hipStream_t stream)
{
  (void)in_sizes; (void)n_in; (void)out_size; (void)ws_size;
  const float* feats = (const float*)d_in[0];
  const int*   pred  = (const int*)d_in[1];
  u16*   ws  = (u16*)d_ws;
  float* out = (float*)d_out;

  PrepPtrs pp;
  const int wIdx[16] = {2,4,6,8,10,12,14,16,18,20,22,24,26,28,30,32};
  for (int i = 0; i < 16; ++i) pp.p[i] = (const float*)d_in[wIdx[i]];
  prep_kernel<<<2048, 256, 0, stream>>>(pp, ws);

  front0_kernel<<<M_NODES/64, 256, 0, stream>>>(feats, (const float*)d_in[2], (const float*)d_in[3], out);

  const size_t LDSB = (size_t)(2*64*264) * sizeof(u16); // 67584 B
  (void)hipFuncSetAttribute((const void*)front_kernel,
                            hipFuncAttributeMaxDynamicSharedMemorySize, (int)LDSB);

  FrontArgs A;
  A.feats = feats; A.pred = pred; A.ws = ws; A.out = out;
  A.embed_b = (const float*)d_in[3];
  A.mp_b1 = (const float*)d_in[5];  A.mp_b2 = (const float*)d_in[7];  A.mp_b3 = (const float*)d_in[9];
  A.cw_b1 = (const float*)d_in[11]; A.cw_b2 = (const float*)d_in[13]; A.cw_b3 = (const float*)d_in[15];
  A.ch_b1 = (const float*)d_in[17]; A.ch_b2 = (const float*)d_in[19]; A.ch_b3 = (const float*)d_in[21];
  A.nw_b1 = (const float*)d_in[23]; A.nw_b2 = (const float*)d_in[25]; A.nw_b3 = (const float*)d_in[27];
  A.nh_b1 = (const float*)d_in[29]; A.nh_b2 = (const float*)d_in[31]; A.nh_b3 = (const float*)d_in[33];

  for (int l = 1; l < 8; ++l){
    A.l = l;
    A.d = (l - 1 < 2) ? (l - 1) : 2;
    front_kernel<<<M_NODES/64, 256, LDSB, stream>>>(A);
  }
}